// Round 1
// baseline (1234.405 us; speedup 1.0000x reference)
//
#include <hip/hip_runtime.h>
#include <hip/hip_bf16.h>

using uint   = unsigned int;
using ushort = unsigned short;
using frag8   = __attribute__((ext_vector_type(8))) short;  // 8 bf16 (4 VGPRs)
using floatx4 = __attribute__((ext_vector_type(4))) float;  // MFMA C/D

__device__ __forceinline__ ushort f2bf(float x) {
    uint u = __builtin_bit_cast(uint, x);
    u += 0x7fffu + ((u >> 16) & 1u);   // round-to-nearest-even (inputs finite)
    return (ushort)(u >> 16);
}

// ---------------------------------------------------------------------------
// Transpose + convert: src f32 [K][128] -> dst bf16 [128][K]. One block = 32 k-rows.
// ---------------------------------------------------------------------------
__global__ __launch_bounds__(256) void transpose_cvt(const float* __restrict__ src,
                                                     ushort* __restrict__ dst, int K) {
    __shared__ ushort t[128 * 40];     // [col][40] padded (80B rows, 16B-aligned)
    const int k0 = blockIdx.x * 32;
    const int tid = threadIdx.x;
#pragma unroll
    for (int it = 0; it < 4; ++it) {
        int idx = it * 256 + tid;              // 0..1023
        int r = idx >> 5, c4 = idx & 31;       // 32 float4 per k-row
        float4 f = *reinterpret_cast<const float4*>(&src[(size_t)(k0 + r) * 128 + c4 * 4]);
        t[(c4 * 4 + 0) * 40 + r] = f2bf(f.x);
        t[(c4 * 4 + 1) * 40 + r] = f2bf(f.y);
        t[(c4 * 4 + 2) * 40 + r] = f2bf(f.z);
        t[(c4 * 4 + 3) * 40 + r] = f2bf(f.w);
    }
    __syncthreads();
#pragma unroll
    for (int it = 0; it < 2; ++it) {
        int idx = it * 256 + tid;              // 0..511
        int col = idx >> 2, q = idx & 3;       // 4x16B per col
        uint4 v = *reinterpret_cast<const uint4*>(&t[col * 40 + q * 8]);
        *reinterpret_cast<uint4*>(&dst[(size_t)col * K + k0 + q * 8]) = v;
    }
}

// Elementwise f32 -> bf16 (for W_agg, which is already B^T layout [128][384])
__global__ void convert_bf(const float* __restrict__ src, ushort* __restrict__ dst, int n) {
    int i = blockIdx.x * 256 + threadIdx.x;
    if (i < n) dst[i] = f2bf(src[i]);
}

// ---------------------------------------------------------------------------
// GEMM: C[M,128] (+)= A[M,K] @ B[K,128]   with A f32 (converted on the fly)
// and B given as bf16 transposed BT[128][K].
// BM=64, BN=128, BK=64. 256 threads = 4 waves; wave -> 32x64 subtile
// (2x4 tiles of mfma_f32_16x16x32_bf16). grid = (M/64, splits), Kseg = K/splits.
// ---------------------------------------------------------------------------
#define LDK 72   // padded LDS row (bf16): stride 144B = 36 banks = 4 mod 32 -> uniform

template <bool ATOMIC, bool HASBIAS>
__global__ __launch_bounds__(256, 2) void gemm_bf16(const float* __restrict__ A,
                                                    const ushort* __restrict__ BT,
                                                    float* __restrict__ C,
                                                    const float* __restrict__ bias,
                                                    int K, int Kseg) {
    __shared__ ushort Alds[64 * LDK];
    __shared__ ushort Blds[128 * LDK];

    const int rb   = blockIdx.x;
    const int ks0  = blockIdx.y * Kseg;
    const int tid  = threadIdx.x;
    const int lane = tid & 63;
    const int wave = tid >> 6;
    const int wr   = (wave >> 1) * 32;   // wave row offset in 64
    const int wc   = (wave & 1) * 64;    // wave col offset in 128
    const int l15  = lane & 15;
    const int quad = lane >> 4;

    floatx4 acc[2][4] = {};

    for (int k0 = ks0; k0 < ks0 + Kseg; k0 += 64) {
        __syncthreads();  // protect LDS from prior-iteration readers
        // ---- stage A: 64 rows x 64 f32 -> bf16 LDS (4 float4 per thread) ----
#pragma unroll
        for (int t = 0; t < 4; ++t) {
            int idx = t * 256 + tid;            // 0..1023
            int r = idx >> 4, kq = idx & 15;    // 16 float4 per row (256B contig / 16 lanes)
            float4 f = *reinterpret_cast<const float4*>(
                &A[(size_t)(rb * 64 + r) * K + k0 + kq * 4]);
            uint2 p;
            p.x = (uint)f2bf(f.x) | ((uint)f2bf(f.y) << 16);
            p.y = (uint)f2bf(f.z) | ((uint)f2bf(f.w) << 16);
            *reinterpret_cast<uint2*>(&Alds[r * LDK + kq * 4]) = p;
        }
        // ---- stage B: 128 rows x 64 bf16 from BT (4x16B per thread) ----
#pragma unroll
        for (int t = 0; t < 4; ++t) {
            int idx = t * 256 + tid;            // 0..1023
            int r = idx >> 3, kq = idx & 7;     // 8x16B per row
            uint4 v = *reinterpret_cast<const uint4*>(&BT[(size_t)r * K + k0 + kq * 8]);
            *reinterpret_cast<uint4*>(&Blds[r * LDK + kq * 8]) = v;
        }
        __syncthreads();
        // ---- MFMA: 2 k-steps of 32 ----
#pragma unroll
        for (int ks = 0; ks < 2; ++ks) {
            frag8 af[2], bf[4];
#pragma unroll
            for (int i = 0; i < 2; ++i)
                af[i] = *reinterpret_cast<const frag8*>(
                    &Alds[(wr + i * 16 + l15) * LDK + ks * 32 + quad * 8]);
#pragma unroll
            for (int j = 0; j < 4; ++j)
                bf[j] = *reinterpret_cast<const frag8*>(
                    &Blds[(wc + j * 16 + l15) * LDK + ks * 32 + quad * 8]);
#pragma unroll
            for (int i = 0; i < 2; ++i)
#pragma unroll
                for (int j = 0; j < 4; ++j)
                    acc[i][j] = __builtin_amdgcn_mfma_f32_16x16x32_bf16(
                        af[i], bf[j], acc[i][j], 0, 0, 0);
        }
    }
    // ---- epilogue: C/D layout col=lane&15, row=quad*4+reg ----
#pragma unroll
    for (int i = 0; i < 2; ++i)
#pragma unroll
        for (int j = 0; j < 4; ++j) {
            int col = wc + j * 16 + l15;
#pragma unroll
            for (int reg = 0; reg < 4; ++reg) {
                size_t row = (size_t)rb * 64 + wr + i * 16 + quad * 4 + reg;
                float v = acc[i][j][reg];
                if (HASBIAS) v += bias[col];
                if (ATOMIC) atomicAdd(&C[row * 128 + col], v);
                else        C[row * 128 + col] = v;
            }
        }
}

// ---------------------------------------------------------------------------
// Build cat=[ret | item_msg | item_msg*group_emb] (f32 [G,384]) + pred output.
// weight is [G,1,1] -> argmax over axis of size 1 is always 0 -> member 0.
// ---------------------------------------------------------------------------
__global__ void catbuild(const float* __restrict__ w, const float* __restrict__ Wcls,
                         const float* __restrict__ bcls, const float* __restrict__ user_msg,
                         const float* __restrict__ item_msg, const float* __restrict__ group_emb,
                         const float* __restrict__ gme, float* __restrict__ cat,
                         float* __restrict__ predout) {
    int gid = blockIdx.x * 256 + threadIdx.x;   // 4096*128 total
    int g = gid >> 7, d = gid & 127;
    float wv = w[g];
    float s0 = wv * Wcls[0] + bcls[0];
    float s1 = wv * Wcls[1] + bcls[1] + (-0.73f);   // class-1 BIAS
    bool pred = s1 > s0;                             // argmax ties -> class 0
    float um = user_msg[(size_t)g * 128 + d];
    float im = item_msg[(size_t)g * 128 + d];
    float ge = group_emb[(size_t)g * 128 + d];
    float sel = gme[(size_t)g * 2048 + d];           // member 0
    size_t cb = (size_t)g * 384;
    cat[cb + d]       = pred ? sel : um;
    cat[cb + 128 + d] = im;
    cat[cb + 256 + d] = im * ge;
    if (d == 0) predout[g] = pred ? 1.0f : 0.0f;
}

// ---------------------------------------------------------------------------
extern "C" void kernel_launch(void* const* d_in, const int* in_sizes, int n_in,
                              void* d_out, int out_size, void* d_ws, size_t ws_size,
                              hipStream_t stream) {
    const float* user_emb   = (const float*)d_in[0];
    const float* item_emb   = (const float*)d_in[1];
    const float* group_emb  = (const float*)d_in[2];
    const float* user_hg    = (const float*)d_in[3];   // [4096,16384]
    const float* item_hg    = (const float*)d_in[4];
    const float* full_hyper = (const float*)d_in[5];   // [36864,4096]
    const float* weight     = (const float*)d_in[6];
    const float* gme        = (const float*)d_in[7];   // [4096,16,128]
    const float* W_agg      = (const float*)d_in[8];   // [128,384]
    const float* b_agg      = (const float*)d_in[9];
    const float* W_cls      = (const float*)d_in[10];
    const float* b_cls      = (const float*)d_in[11];

    float* out_norm = (float*)d_out;               // [36864,128]
    float* out_msg  = out_norm + (size_t)36864 * 128;
    float* out_pred = out_msg + (size_t)4096 * 128;

    char* ws = (char*)d_ws;
    float*  user_msg = (float*)(ws + 0);           // 2 MB
    float*  item_msg = (float*)(ws + 2097152);     // 2 MB
    float*  cat      = (float*)(ws + 4194304);     // 6 MB  [4096,384]
    ushort* userT    = (ushort*)(ws + 10485760);   // 4 MB  bf16 [128,16384]
    ushort* itemT    = (ushort*)(ws + 14680064);   // 4 MB
    ushort* msgT     = (ushort*)(ws + 18874368);   // 1 MB  bf16 [128,4096]
    ushort* waggT    = (ushort*)(ws + 19922944);   // 96 KB bf16 [128,384]

    // zero split-K accumulators (ws is re-poisoned every call)
    hipMemsetAsync(d_ws, 0, 4194304, stream);

    transpose_cvt<<<512, 256, 0, stream>>>(user_emb, userT, 16384);
    transpose_cvt<<<512, 256, 0, stream>>>(item_emb, itemT, 16384);
    convert_bf<<<192, 256, 0, stream>>>(W_agg, waggT, 128 * 384);

    // user_msg / item_msg: split-K=8 -> 512 blocks each (2 blocks/CU)
    gemm_bf16<true, false><<<dim3(64, 8), 256, 0, stream>>>(user_hg, userT, user_msg,
                                                            nullptr, 16384, 2048);
    gemm_bf16<true, false><<<dim3(64, 8), 256, 0, stream>>>(item_hg, itemT, item_msg,
                                                            nullptr, 16384, 2048);

    catbuild<<<2048, 256, 0, stream>>>(weight, W_cls, b_cls, user_msg, item_msg,
                                       group_emb, gme, cat, out_pred);

    // msg = cat @ W_agg.T + b_agg  (W_agg is already BT layout)
    gemm_bf16<false, true><<<dim3(64, 1), 256, 0, stream>>>(cat, waggT, out_msg,
                                                            b_agg, 384, 384);
    transpose_cvt<<<128, 256, 0, stream>>>(out_msg, msgT, 4096);

    // norm_emb = full_hyper @ msg  (576 row-blocks)
    gemm_bf16<false, false><<<dim3(576, 1), 256, 0, stream>>>(full_hyper, msgT, out_norm,
                                                              nullptr, 4096, 4096);
}